// Round 1
// baseline (400.972 us; speedup 1.0000x reference)
//
#include <hip/hip_runtime.h>
#include <math.h>

#define DD 1024
#define HH 2048

// ---------------- P = (W1^T @ W3^T) .* W2  ----------------
// P[m*H+k] = (sum_i W1[i*H+m] * W3[k*D+i]) * W2[m*H+k]
__global__ __launch_bounds__(256) void k_gemm_P(const float* __restrict__ W1,
                                                const float* __restrict__ W2,
                                                const float* __restrict__ W3,
                                                float* __restrict__ P) {
    __shared__ float As[32][65];   // As[kk][m]  = W1[(i0+kk)*H + m0+m]
    __shared__ float Bs[32][65];   // Bs[kk][k]  = W3[(k0+k)*D + i0+kk]
    const int m0 = blockIdx.y * 64;
    const int k0 = blockIdx.x * 64;
    const int t = threadIdx.x;
    const int tx = t & 15, ty = t >> 4;
    float acc[4][4] = {};
    for (int i0 = 0; i0 < DD; i0 += 32) {
        #pragma unroll
        for (int q = 0; q < 8; ++q) {
            int l = q * 256 + t;
            int kk = l >> 6, m = l & 63;           // coalesced over m
            As[kk][m] = W1[(i0 + kk) * HH + m0 + m];
        }
        #pragma unroll
        for (int q = 0; q < 8; ++q) {
            int l = q * 256 + t;
            int kk = l & 31, k = l >> 5;           // coalesced over i(=kk)
            Bs[kk][k] = W3[(k0 + k) * DD + i0 + kk];
        }
        __syncthreads();
        #pragma unroll
        for (int kk = 0; kk < 32; ++kk) {
            float av[4], bv[4];
            #pragma unroll
            for (int a = 0; a < 4; ++a) av[a] = As[kk][ty * 4 + a];
            #pragma unroll
            for (int b = 0; b < 4; ++b) bv[b] = Bs[kk][tx * 4 + b];
            #pragma unroll
            for (int a = 0; a < 4; ++a)
                #pragma unroll
                for (int b = 0; b < 4; ++b)
                    acc[a][b] += av[a] * bv[b];
        }
        __syncthreads();
    }
    #pragma unroll
    for (int a = 0; a < 4; ++a) {
        int m = m0 + ty * 4 + a;
        #pragma unroll
        for (int b = 0; b < 4; ++b) {
            int k = k0 + tx * 4 + b;
            P[m * HH + k] = acc[a][b] * W2[m * HH + k];
        }
    }
}

// ---------------- init: x=xs=xacc=x0, logq0 ----------------
__global__ __launch_bounds__(1024) void k_init(const float* __restrict__ x0,
                                               float* x, float* xs, float* xacc,
                                               float* logq) {
    int j = threadIdx.x;  // 1024 threads, 1 block
    float xv = x0[j];
    x[j] = xv; xs[j] = xv; xacc[j] = xv;
    float s = xv * xv;
    #pragma unroll
    for (int o = 32; o > 0; o >>= 1) s += __shfl_down(s, o, 64);
    __shared__ float red[16];
    if ((j & 63) == 0) red[j >> 6] = s;
    __syncthreads();
    if (j == 0) {
        float r = 0.f;
        #pragma unroll
        for (int q = 0; q < 16; ++q) r += red[q];
        // log(2*pi) = 1.8378770664093453
        logq[0] = -0.5f * r - 0.5f * 1024.0f * 1.8378770664093453f;
    }
}

// ---------------- layer 1 partial: part1[s][j] = sum_{i in seg s} xs[i]*W1[i,j]
__global__ __launch_bounds__(256) void k_l1p(const float* __restrict__ W1,
                                             const float* __restrict__ xs,
                                             float* __restrict__ part1) {
    int b = blockIdx.x;                 // 256 blocks: 32 segs x 8 j-chunks
    int s = b >> 3, j = ((b & 7) << 8) + threadIdx.x;
    const float* xw = xs + s * 32;
    const float* Wp = W1 + (s * 32) * HH + j;
    float acc = 0.f;
    #pragma unroll 8
    for (int ii = 0; ii < 32; ++ii) acc += xw[ii] * Wp[ii * HH];
    part1[s * HH + j] = acc;
}

__global__ __launch_bounds__(256) void k_l1r(const float* __restrict__ part1,
                                             const float* __restrict__ b1,
                                             const float* __restrict__ wt, float t,
                                             float* __restrict__ h1, float* __restrict__ u) {
    int j = blockIdx.x * 256 + threadIdx.x;   // 8 blocks
    float a = b1[j] + t * wt[j];
    for (int s = 0; s < 32; ++s) a += part1[s * HH + j];
    float h = tanhf(a);
    h1[j] = h; u[j] = 1.f - h * h;
}

// ---------------- layer 2 partial ----------------
__global__ __launch_bounds__(256) void k_l2p(const float* __restrict__ W2,
                                             const float* __restrict__ h1,
                                             float* __restrict__ part2) {
    int b = blockIdx.x;                 // 256 blocks: 32 segs(64) x 8 j-chunks
    int s = b >> 3, j = ((b & 7) << 8) + threadIdx.x;
    const float* hp = h1 + s * 64;
    const float* Wp = W2 + (s * 64) * HH + j;
    float acc = 0.f;
    #pragma unroll 8
    for (int mm = 0; mm < 64; ++mm) acc += hp[mm] * Wp[mm * HH];
    part2[s * HH + j] = acc;
}

__global__ __launch_bounds__(256) void k_l2r(const float* __restrict__ part2,
                                             const float* __restrict__ b2,
                                             float* __restrict__ h2, float* __restrict__ w) {
    int j = blockIdx.x * 256 + threadIdx.x;   // 8 blocks
    float a = b2[j];
    for (int s = 0; s < 32; ++s) a += part2[s * HH + j];
    float h = tanhf(a);
    h2[j] = h; w[j] = 1.f - h * h;
}

// ---------------- layer 3 partial (v) ----------------
__global__ __launch_bounds__(256) void k_l3p(const float* __restrict__ W3,
                                             const float* __restrict__ h2,
                                             float* __restrict__ part3) {
    int b = blockIdx.x;                 // 256 blocks: 64 segs(32) x 4 j-chunks
    int s = b >> 2, j = ((b & 3) << 8) + threadIdx.x;
    const float* hp = h2 + s * 32;
    const float* Wp = W3 + (s * 32) * DD + j;
    float acc = 0.f;
    #pragma unroll 8
    for (int kk = 0; kk < 32; ++kk) acc += hp[kk] * Wp[kk * DD];
    part3[s * DD + j] = acc;
}

__global__ __launch_bounds__(256) void k_vred(const float* __restrict__ part3,
                                              const float* __restrict__ b3,
                                              float* __restrict__ v) {
    int j = blockIdx.x * 256 + threadIdx.x;   // 4 blocks
    float a = b3[j];
    for (int s = 0; s < 64; ++s) a += part3[s * DD + j];
    v[j] = a;
}

// ---------------- divergence partial: div = u^T P w ----------------
__global__ __launch_bounds__(256) void k_divp(const float* __restrict__ P,
                                              const float* __restrict__ u,
                                              const float* __restrict__ w,
                                              float* __restrict__ divpart) {
    int b = blockIdx.x;   // 256 blocks x 8 rows
    int t = threadIdx.x;
    float acc = 0.f;
    #pragma unroll
    for (int mm = 0; mm < 8; ++mm) {
        int m = b * 8 + mm;
        float um = u[m];
        const float* Pp = P + (size_t)m * HH;
        float s = 0.f;
        #pragma unroll
        for (int kq = 0; kq < 8; ++kq) {
            int k = t + kq * 256;
            s += Pp[k] * w[k];
        }
        acc += um * s;
    }
    #pragma unroll
    for (int o = 32; o > 0; o >>= 1) acc += __shfl_down(acc, o, 64);
    __shared__ float red[4];
    if ((t & 63) == 0) red[t >> 6] = acc;
    __syncthreads();
    if (t == 0) divpart[b] = red[0] + red[1] + red[2] + red[3];
}

// ---------------- RK4 stage update ----------------
__global__ __launch_bounds__(1024) void k_stage(const float* __restrict__ v,
                                                const float* __restrict__ divpart,
                                                float* x, float* xs, float* xacc,
                                                float* logq, int s, float dt) {
    __shared__ float dred[256];
    int t = threadIdx.x;
    if (t < 256) dred[t] = divpart[t];
    __syncthreads();
    for (int o = 128; o > 0; o >>= 1) {
        if (t < o) dred[t] += dred[t + o];
        __syncthreads();
    }
    float div = dred[0];
    float c = (s == 0 || s == 3) ? 1.f : 2.f;
    float coef = c * dt / 6.f;
    float vv = v[t];
    float xa = xacc[t] + coef * vv;
    xacc[t] = xa;
    if (s < 3) {
        float a = (s == 2) ? dt : 0.5f * dt;
        xs[t] = x[t] + a * vv;
    } else {
        x[t] = xa;
        xs[t] = xa;
    }
    if (t == 0) logq[0] -= coef * div;
}

// ---------------- output ----------------
__global__ void k_out(const float* __restrict__ x, const float* __restrict__ logq,
                      float* __restrict__ out) {
    int t = blockIdx.x * 256 + threadIdx.x;
    if (t < DD) out[t] = x[t];
    if (t == DD) out[DD] = logq[0];
}

extern "C" void kernel_launch(void* const* d_in, const int* in_sizes, int n_in,
                              void* d_out, int out_size, void* d_ws, size_t ws_size,
                              hipStream_t stream) {
    const float* x0 = (const float*)d_in[0];
    const float* W1 = (const float*)d_in[1];
    const float* b1 = (const float*)d_in[2];
    const float* wt = (const float*)d_in[3];
    const float* W2 = (const float*)d_in[4];
    const float* b2 = (const float*)d_in[5];
    const float* W3 = (const float*)d_in[6];
    const float* b3 = (const float*)d_in[7];
    float* out = (float*)d_out;

    float* ws = (float*)d_ws;
    float* P     = ws;                            // 4M floats (16 MB)
    float* part1 = P + (size_t)HH * HH;           // 32*2048
    float* part2 = part1 + 32 * HH;               // 32*2048
    float* part3 = part2 + 32 * HH;               // 64*1024
    float* h1    = part3 + 64 * DD;
    float* u     = h1 + HH;
    float* h2    = u + HH;
    float* w     = h2 + HH;
    float* v     = w + HH;
    float* divpart = v + DD;                      // 256
    float* x     = divpart + 256;
    float* xs    = x + DD;
    float* xacc  = xs + DD;
    float* logq  = xacc + DD;                     // 1

    dim3 g(32, 32);
    k_gemm_P<<<g, 256, 0, stream>>>(W1, W2, W3, P);
    k_init<<<1, 1024, 0, stream>>>(x0, x, xs, xacc, logq);

    const float dt = 0.5f;
    for (int step = 0; step < 2; ++step) {
        float t0 = step * dt;
        float ts[4] = {t0, t0 + 0.25f, t0 + 0.25f, t0 + 0.5f};
        for (int s = 0; s < 4; ++s) {
            k_l1p<<<256, 256, 0, stream>>>(W1, xs, part1);
            k_l1r<<<8, 256, 0, stream>>>(part1, b1, wt, ts[s], h1, u);
            k_l2p<<<256, 256, 0, stream>>>(W2, h1, part2);
            k_l2r<<<8, 256, 0, stream>>>(part2, b2, h2, w);
            k_l3p<<<256, 256, 0, stream>>>(W3, h2, part3);
            k_vred<<<4, 256, 0, stream>>>(part3, b3, v);
            k_divp<<<256, 256, 0, stream>>>(P, u, w, divpart);
            k_stage<<<1, 1024, 0, stream>>>(v, divpart, x, xs, xacc, logq, s, dt);
        }
    }
    k_out<<<5, 256, 0, stream>>>(x, logq, out);
}

// Round 2
// 221.339 us; speedup vs baseline: 1.8116x; 1.8116x over previous
//
#include <hip/hip_runtime.h>
#include <math.h>

#define DD 1024
#define HH 2048

typedef float f32x4 __attribute__((ext_vector_type(4)));
typedef short short8 __attribute__((ext_vector_type(8)));

__device__ __forceinline__ float b2f(unsigned short u) {
    return __uint_as_float(((unsigned int)u) << 16);
}
__device__ __forceinline__ unsigned short f2b(float f) {
    unsigned int x = __float_as_uint(f);
    unsigned int r = (x + 0x7FFFu + ((x >> 16) & 1u)) >> 16;
    return (unsigned short)r;
}

// ---------------- f32 -> bf16 convert (n multiple of 4) ----------------
__global__ __launch_bounds__(256) void k_f2b(const float* __restrict__ in,
                                             unsigned short* __restrict__ out, int n) {
    int i = (blockIdx.x * 256 + threadIdx.x) * 4;
    if (i < n) {
        float4 v = *(const float4*)(in + i);
        ushort4 o;
        o.x = f2b(v.x); o.y = f2b(v.y); o.z = f2b(v.z); o.w = f2b(v.w);
        *(ushort4*)(out + i) = o;
    }
}

// ---------------- W1 [1024][2048] f32 -> W1T [2048][1024] bf16 ----------------
__global__ __launch_bounds__(256) void k_transpose(const float* __restrict__ W1,
                                                   unsigned short* __restrict__ W1T) {
    __shared__ float tile[64][65];
    const int i0 = blockIdx.x * 64;   // 16
    const int m0 = blockIdx.y * 64;   // 32
    const int t = threadIdx.x;
    const int c = t & 63, rb = t >> 6;
    #pragma unroll
    for (int p = 0; p < 16; ++p) {
        int rr = p * 4 + rb;
        tile[rr][c] = W1[(i0 + rr) * HH + m0 + c];
    }
    __syncthreads();
    #pragma unroll
    for (int p = 0; p < 16; ++p) {
        int rp = p * 4 + rb;
        W1T[(m0 + rp) * DD + i0 + c] = f2b(tile[c][rp]);
    }
}

// ---------------- P = (W1^T @ W3^T) .* W2, bf16 MFMA ----------------
// A[m][i] = W1T[m][i] (bf16), B[i][k] = W3[k][i] -> B-frag rows are W3b rows.
// P_bf16[m][k] = (sum_i A*B) * W2[m][k]
__global__ __launch_bounds__(256) void k_gemmP(const unsigned short* __restrict__ W1T,
                                               const unsigned short* __restrict__ W3b,
                                               const float* __restrict__ W2,
                                               unsigned short* __restrict__ Pb) {
    __shared__ unsigned short At[128][40];  // 80B rows: 16B-aligned, ~2-way banks
    __shared__ unsigned short Bt[128][40];
    const int m0 = blockIdx.y * 128;
    const int k0 = blockIdx.x * 128;
    const int t = threadIdx.x;
    const int r = t & 127, half = t >> 7;
    const int wv = t >> 6, l = t & 63;
    const int wr = wv >> 1, wc = wv & 1;
    const int fr = l & 15, fg = l >> 4;

    f32x4 acc[4][4] = {};
    for (int i0 = 0; i0 < DD; i0 += 32) {
        {
            const float4* sa = (const float4*)(W1T + (m0 + r) * DD + i0 + half * 16);
            const float4* sb = (const float4*)(W3b + (k0 + r) * DD + i0 + half * 16);
            float4 a0 = sa[0], a1 = sa[1];
            float4 b0 = sb[0], b1 = sb[1];
            float4* da = (float4*)&At[r][half * 16];
            float4* db = (float4*)&Bt[r][half * 16];
            da[0] = a0; da[1] = a1;
            db[0] = b0; db[1] = b1;
        }
        __syncthreads();
        short8 af[4], bf[4];
        #pragma unroll
        for (int a = 0; a < 4; ++a)
            af[a] = *(const short8*)&At[wr * 64 + a * 16 + fr][fg * 8];
        #pragma unroll
        for (int b = 0; b < 4; ++b)
            bf[b] = *(const short8*)&Bt[wc * 64 + b * 16 + fr][fg * 8];
        #pragma unroll
        for (int a = 0; a < 4; ++a)
            #pragma unroll
            for (int b = 0; b < 4; ++b)
                acc[a][b] = __builtin_amdgcn_mfma_f32_16x16x32_bf16(af[a], bf[b], acc[a][b], 0, 0, 0);
        __syncthreads();
    }
    // C/D: col = lane&15, row = (lane>>4)*4 + reg   [verified m89/m91]
    #pragma unroll
    for (int a = 0; a < 4; ++a) {
        #pragma unroll
        for (int b = 0; b < 4; ++b) {
            #pragma unroll
            for (int j = 0; j < 4; ++j) {
                int row = m0 + wr * 64 + a * 16 + fg * 4 + j;
                int col = k0 + wc * 64 + b * 16 + fr;
                size_t idx = (size_t)row * HH + col;
                Pb[idx] = f2b(acc[a][b][j] * W2[idx]);
            }
        }
    }
}

// ---------------- init ----------------
__global__ __launch_bounds__(1024) void k_init(const float* __restrict__ x0,
                                               float* x, float* xs, float* xacc,
                                               float* logq) {
    int j = threadIdx.x;
    float xv = x0[j];
    x[j] = xv; xs[j] = xv; xacc[j] = xv;
    float s = xv * xv;
    #pragma unroll
    for (int o = 32; o > 0; o >>= 1) s += __shfl_down(s, o, 64);
    __shared__ float red[16];
    if ((j & 63) == 0) red[j >> 6] = s;
    __syncthreads();
    if (j == 0) {
        float r = 0.f;
        #pragma unroll
        for (int q = 0; q < 16; ++q) r += red[q];
        logq[0] = -0.5f * r - 0.5f * 1024.0f * 1.8378770664093453f;
    }
}

// ---------------- layer1 partial: part1[s][j] = sum_{i in seg} xs[i]*W1[i,j] ----------------
__global__ __launch_bounds__(256) void k_l1p(const float* __restrict__ W1,
                                             const float* __restrict__ xs,
                                             float* __restrict__ part1) {
    int b = blockIdx.x;                 // 256: 32 segs x 8 chunks
    int s = b >> 3, j = ((b & 7) << 8) + threadIdx.x;
    const float* xw = xs + s * 32;
    const float* Wp = W1 + (s * 32) * HH + j;
    float acc = 0.f;
    #pragma unroll 8
    for (int ii = 0; ii < 32; ++ii) acc += xw[ii] * Wp[ii * HH];
    part1[s * HH + j] = acc;
}

// ---------------- fused: h1/u from part1, then part2 = h1seg @ W2 ----------------
__global__ __launch_bounds__(256) void k_l2(const float* __restrict__ part1,
                                            const float* __restrict__ b1,
                                            const float* __restrict__ wt, float tcur,
                                            const float* __restrict__ W2f,
                                            const unsigned short* __restrict__ W2b,
                                            float* __restrict__ u,
                                            float* __restrict__ part2) {
    __shared__ float red[4][64];
    __shared__ float h1s[64];
    int b = blockIdx.x;                 // 256: 32 m-segs x 8 chunks
    int s = b >> 3, jc = b & 7;
    int t = threadIdx.x;
    int ml = t & 63, g = t >> 6;
    float p = 0.f;
    #pragma unroll
    for (int q = 0; q < 8; ++q) p += part1[(g * 8 + q) * HH + s * 64 + ml];
    red[g][ml] = p;
    __syncthreads();
    if (t < 64) {
        int m = s * 64 + t;
        float pre = b1[m] + tcur * wt[m] + red[0][t] + red[1][t] + red[2][t] + red[3][t];
        float h = tanhf(pre);
        h1s[t] = h;
        if (jc == 0) u[m] = 1.f - h * h;
    }
    __syncthreads();
    int j = jc * 256 + t;
    float acc = 0.f;
    if (W2b) {
        const unsigned short* Wp = W2b + (s * 64) * HH + j;
        #pragma unroll 8
        for (int mm = 0; mm < 64; ++mm) acc += h1s[mm] * b2f(Wp[mm * HH]);
    } else {
        const float* Wp = W2f + (s * 64) * HH + j;
        #pragma unroll 8
        for (int mm = 0; mm < 64; ++mm) acc += h1s[mm] * Wp[mm * HH];
    }
    part2[s * HH + j] = acc;
}

// ---------------- fused: h2/w from part2, then part3 = h2seg @ W3 ----------------
__global__ __launch_bounds__(256) void k_l3(const float* __restrict__ part2,
                                            const float* __restrict__ b2,
                                            const unsigned short* __restrict__ W3b,
                                            float* __restrict__ w,
                                            float* __restrict__ part3) {
    __shared__ float red[4][64];
    __shared__ float h2s[64];
    int b = blockIdx.x;                 // 128: 32 k-segs x 4 chunks
    int ss = b >> 2, jc = b & 3;
    int t = threadIdx.x;
    int kl = t & 63, g = t >> 6;
    float p = 0.f;
    #pragma unroll
    for (int q = 0; q < 8; ++q) p += part2[(g * 8 + q) * HH + ss * 64 + kl];
    red[g][kl] = p;
    __syncthreads();
    if (t < 64) {
        int k = ss * 64 + t;
        float pre = b2[k] + red[0][t] + red[1][t] + red[2][t] + red[3][t];
        float h = tanhf(pre);
        h2s[t] = h;
        if (jc == 0) w[k] = 1.f - h * h;
    }
    __syncthreads();
    int j = jc * 256 + t;
    const unsigned short* Wp = W3b + (ss * 64) * DD + j;
    float acc = 0.f;
    #pragma unroll 8
    for (int kk = 0; kk < 64; ++kk) acc += h2s[kk] * b2f(Wp[kk * DD]);
    part3[ss * DD + j] = acc;
}

// ---------------- div partials (blocks 0..255) + v reduce (blocks 256..259) ----------------
__global__ __launch_bounds__(256) void k_divv(const unsigned short* __restrict__ Pb,
                                              const float* __restrict__ u,
                                              const float* __restrict__ w,
                                              const float* __restrict__ part3,
                                              const float* __restrict__ b3,
                                              float* __restrict__ divpart,
                                              float* __restrict__ v) {
    int b = blockIdx.x;
    int t = threadIdx.x;
    if (b < 256) {
        float wv[8];
        #pragma unroll
        for (int kq = 0; kq < 8; ++kq) wv[kq] = w[t + kq * 256];
        float acc = 0.f;
        #pragma unroll
        for (int mm = 0; mm < 8; ++mm) {
            int m = b * 8 + mm;
            const unsigned short* Pp = Pb + (size_t)m * HH;
            float s = 0.f;
            #pragma unroll
            for (int kq = 0; kq < 8; ++kq) s += b2f(Pp[t + kq * 256]) * wv[kq];
            acc += u[m] * s;
        }
        #pragma unroll
        for (int o = 32; o > 0; o >>= 1) acc += __shfl_down(acc, o, 64);
        __shared__ float red[4];
        if ((t & 63) == 0) red[t >> 6] = acc;
        __syncthreads();
        if (t == 0) divpart[b] = red[0] + red[1] + red[2] + red[3];
    } else {
        int j = (b - 256) * 256 + t;
        float a = b3[j];
        for (int ss = 0; ss < 32; ++ss) a += part3[ss * DD + j];
        v[j] = a;
    }
}

// ---------------- RK4 stage update ----------------
__global__ __launch_bounds__(1024) void k_stage(const float* __restrict__ v,
                                                const float* __restrict__ divpart,
                                                float* x, float* xs, float* xacc,
                                                float* logq, int s, float dt) {
    __shared__ float dred[256];
    int t = threadIdx.x;
    if (t < 256) dred[t] = divpart[t];
    __syncthreads();
    for (int o = 128; o > 0; o >>= 1) {
        if (t < o) dred[t] += dred[t + o];
        __syncthreads();
    }
    float div = dred[0];
    float c = (s == 0 || s == 3) ? 1.f : 2.f;
    float coef = c * dt / 6.f;
    float vv = v[t];
    float xa = xacc[t] + coef * vv;
    xacc[t] = xa;
    if (s < 3) {
        float a = (s == 2) ? dt : 0.5f * dt;
        xs[t] = x[t] + a * vv;
    } else {
        x[t] = xa;
        xs[t] = xa;
    }
    if (t == 0) logq[0] -= coef * div;
}

// ---------------- output ----------------
__global__ void k_out(const float* __restrict__ x, const float* __restrict__ logq,
                      float* __restrict__ out) {
    int t = blockIdx.x * 256 + threadIdx.x;
    if (t < DD) out[t] = x[t];
    if (t == DD) out[DD] = logq[0];
}

extern "C" void kernel_launch(void* const* d_in, const int* in_sizes, int n_in,
                              void* d_out, int out_size, void* d_ws, size_t ws_size,
                              hipStream_t stream) {
    const float* x0 = (const float*)d_in[0];
    const float* W1 = (const float*)d_in[1];
    const float* b1 = (const float*)d_in[2];
    const float* wt = (const float*)d_in[3];
    const float* W2 = (const float*)d_in[4];
    const float* b2 = (const float*)d_in[5];
    const float* W3 = (const float*)d_in[6];
    const float* b3 = (const float*)d_in[7];
    float* out = (float*)d_out;

    char* ws = (char*)d_ws;
    const size_t MB = 1024 * 1024;
    unsigned short* Pb  = (unsigned short*)(ws + 0);        // 8 MB (2048x2048 bf16)
    unsigned short* W1T = (unsigned short*)(ws + 8 * MB);   // 4 MB (2048x1024 bf16)
    unsigned short* W3b = (unsigned short*)(ws + 12 * MB);  // 4 MB (2048x1024 bf16)
    float* fbase = (float*)(ws + 16 * MB);
    float* part1 = fbase;                  // 32*2048
    float* part2 = part1 + 32 * HH;        // 32*2048
    float* part3 = part2 + 32 * HH;        // 32*1024
    float* u     = part3 + 32 * DD;        // 2048
    float* w     = u + HH;                 // 2048
    float* v     = w + HH;                 // 1024
    float* divpart = v + DD;               // 256
    float* x     = divpart + 256;          // 1024
    float* xs    = x + DD;                 // 1024
    float* xacc  = xs + DD;                // 1024
    float* logq  = xacc + DD;              // 1
    unsigned short* W2b = nullptr;         // optional 8 MB at 17 MB
    if (ws_size >= 26 * MB) W2b = (unsigned short*)(ws + 17 * MB);

    // ---- precompute (once per call) ----
    k_f2b<<<(HH * DD) / 1024, 256, 0, stream>>>(W3, W3b, HH * DD);
    if (W2b) k_f2b<<<(HH * HH) / 1024, 256, 0, stream>>>(W2, W2b, HH * HH);
    k_transpose<<<dim3(16, 32), 256, 0, stream>>>(W1, W1T);
    k_gemmP<<<dim3(16, 16), 256, 0, stream>>>(W1T, W3b, W2, Pb);
    k_init<<<1, 1024, 0, stream>>>(x0, x, xs, xacc, logq);

    const float dt = 0.5f;
    for (int step = 0; step < 2; ++step) {
        float t0 = step * dt;
        float tsv[4] = {t0, t0 + 0.25f, t0 + 0.25f, t0 + 0.5f};
        for (int s = 0; s < 4; ++s) {
            k_l1p<<<256, 256, 0, stream>>>(W1, xs, part1);
            k_l2<<<256, 256, 0, stream>>>(part1, b1, wt, tsv[s], W2, W2b, u, part2);
            k_l3<<<128, 256, 0, stream>>>(part2, b2, W3b, w, part3);
            k_divv<<<260, 256, 0, stream>>>(Pb, u, w, part3, b3, divpart, v);
            k_stage<<<1, 1024, 0, stream>>>(v, divpart, x, xs, xacc, logq, s, dt);
        }
    }
    k_out<<<5, 256, 0, stream>>>(x, logq, out);
}